// Round 1
// 93.717 us; speedup vs baseline: 1.0235x; 1.0235x over previous
//
#include <hip/hip_runtime.h>
#include <math.h>

// B=2, L=2048, D=512, N=64 -> M=4096 tokens.
//   y[t,d] = x[t,d] * softplus((x@W1+b1)[t,d]) * s[t]
//   s[t]   = dot(x_t@W2+b2, x_t@W3+b3)
//   exp(delta*A) multiplies h=0 -> contributes zero; A unused.
//
// v2: s_kernel + y_kernel FUSED into one kernel (s[t] only needs the block's
// own 16 x-rows).  Eliminates the 4MB xh HBM round-trip, the second 8MB x
// read, one launch + dependency stall, and converts y stores to fully
// coalesced float4 rows staged through LDS.
#define DDIM 512

typedef _Float16 f16;
typedef _Float16 f16x4 __attribute__((ext_vector_type(4)));
typedef _Float16 f16x8 __attribute__((ext_vector_type(8)));
typedef float f32x4 __attribute__((ext_vector_type(4)));

__device__ __forceinline__ float softplusf(float v) {
    return (v > 20.0f) ? v : log1pf(__expf(v));
}

// ---------------------------------------------------------------------------
// prep_w: 20 blocks x 256 thr.  W1 -> w1t slabs (nt 0..31); W2 -> w23 nt 0..3;
// W3 -> w23 nt 4..7.  Each block transposes a 512k x 32col strip.
// (unchanged from verified v1)
// ---------------------------------------------------------------------------
__global__ __launch_bounds__(256) void prep_w(
    const float* __restrict__ W1, const float* __restrict__ W2,
    const float* __restrict__ W3, f16* __restrict__ w1t, f16* __restrict__ w23)
{
    __shared__ __align__(16) f16 lt[32][520];
    const int tid  = threadIdx.x;
    const int wb   = blockIdx.x;
    const int wv   = tid >> 6;
    const int lane = tid & 63;
    const int q    = lane >> 4;
    const int l15  = lane & 15;

    const float* src; int srcRS, col0; f16* dst;
    if (wb < 16)      { src = W1; srcRS = DDIM; col0 = wb * 32;
                        dst = w1t + (size_t)wb * 2 * 16 * 512; }
    else if (wb < 18) { src = W2; srcRS = 64;  col0 = (wb - 16) * 32;
                        dst = w23 + (size_t)(wb - 16) * 2 * 16 * 512; }
    else              { src = W3; srcRS = 64;  col0 = (wb - 18) * 32;
                        dst = w23 + (size_t)(4 + (wb - 18) * 2) * 16 * 512; }
#pragma unroll
    for (int i = 0; i < 16; ++i) {
        int f  = tid + 256 * i;
        int k  = f >> 3;
        int c4 = (f & 7) * 4;
        float4 v = *(const float4*)(src + (size_t)k * srcRS + col0 + c4);
        lt[c4 + 0][k] = (f16)v.x; lt[c4 + 1][k] = (f16)v.y;
        lt[c4 + 2][k] = (f16)v.z; lt[c4 + 3][k] = (f16)v.w;
    }
    __syncthreads();
#pragma unroll
    for (int j = 0; j < 8; ++j) {
        int s   = wv * 8 + j;          // 0..31
        int ntL = s >> 4;              // 0..1
        int kt  = s & 15;
        f16x8 vv = *(const f16x8*)&lt[ntL * 16 + l15][kt * 32 + q * 8];
        *(f16x8*)(dst + (size_t)(ntL * 16 + kt) * 512 + lane * 8) = vv;
    }
}

// ---------------------------------------------------------------------------
// fused_sy: 256 blocks x 512 thr (8 waves), 16 tokens/block, all 512 d-cols.
// Phase 0: stage x rows -> xf (fp32, epilogue) + xs (f16 fragment layout).
// Phase 1: s — wave wv computes ONE chain: B(nt=wv) for wv<4, C(nt=wv-4) for
//          wv>=4 (w23 slab index == wv).  Partials + bias -> sp LDS.
// Phase 2: waves 0..3 pair-reduce s[t] = sum_n B*C -> s_lds (overlaps with
//          waves 4..7 starting the y-GEMM).
// Phase 3: y-GEMM — wave wv owns n-tiles wv*4..wv*4+3 (64 MFMAs/wave), A from
//          LDS, B direct global->VGPR from pre-swizzled w1t slabs (L2-hot).
// Phase 4: epilogue in place into xf, then coalesced float4 row copy-out.
// ---------------------------------------------------------------------------
__global__ __launch_bounds__(512) void fused_sy(
    const float* __restrict__ x, const f16* __restrict__ w1t,
    const f16* __restrict__ w23, const float* __restrict__ b1,
    const float* __restrict__ b2, const float* __restrict__ b3,
    float* __restrict__ y)
{
    __shared__ __align__(16) float xf[16][516];   // fp32 x, then y (in place)
    __shared__ __align__(16) f16  xs[16][520];    // f16 A-fragments
    __shared__ float sp[8][16][17];               // s partials (pad 17: no 4-way)
    __shared__ float s_lds[16];

    const int tid  = threadIdx.x;
    const int wv   = tid >> 6;
    const int lane = tid & 63;
    const int q    = lane >> 4;
    const int l15  = lane & 15;
    const int tb   = blockIdx.x * 16;

    // ---- Phase 0: stage x (coalesced float4; 16 rows x 512 cols) ----
#pragma unroll
    for (int it = 0; it < 4; ++it) {
        int f   = tid + 512 * it;
        int row = f >> 7;              // 128 float4 per row
        int c4  = (f & 127) * 4;
        float4 v = *(const float4*)(x + (size_t)(tb + row) * DDIM + c4);
        *(float4*)&xf[row][c4] = v;
        f16x4 h = {(f16)v.x, (f16)v.y, (f16)v.z, (f16)v.w};
        *(f16x4*)&xs[row][c4] = h;
    }
    __syncthreads();

    // ---- Phase 1: s partial chains (2 independent K-halves for dep hiding) --
    {
        const f16* wS = w23 + (size_t)wv * 16 * 512 + lane * 8;
        f32x4 aclo = (f32x4){0.f, 0.f, 0.f, 0.f};
        f32x4 achi = (f32x4){0.f, 0.f, 0.f, 0.f};
#pragma unroll
        for (int kt = 0; kt < 8; ++kt) {
            f16x8 a0 = *(const f16x8*)&xs[l15][kt * 32 + q * 8];
            f16x8 a1 = *(const f16x8*)&xs[l15][(kt + 8) * 32 + q * 8];
            f16x8 w0 = *(const f16x8*)(wS + (size_t)kt * 512);
            f16x8 w1 = *(const f16x8*)(wS + (size_t)(kt + 8) * 512);
            aclo = __builtin_amdgcn_mfma_f32_16x16x32_f16(a0, w0, aclo, 0, 0, 0);
            achi = __builtin_amdgcn_mfma_f32_16x16x32_f16(a1, w1, achi, 0, 0, 0);
        }
        float bias = (wv < 4) ? b2[wv * 16 + l15] : b3[(wv - 4) * 16 + l15];
#pragma unroll
        for (int r = 0; r < 4; ++r)
            sp[wv][q * 4 + r][l15] = aclo[r] + achi[r] + bias;
    }
    __syncthreads();

    // ---- Phase 2: pair-reduce s[t] (waves 0..3 only; overlaps y of 4..7) ----
    if (tid < 256) {
        int t = tid >> 4, n16 = tid & 15;
        float v = 0.f;
#pragma unroll
        for (int g = 0; g < 4; ++g)
            v += sp[g][t][n16] * sp[4 + g][t][n16];
        v += __shfl_xor(v, 1); v += __shfl_xor(v, 2);
        v += __shfl_xor(v, 4); v += __shfl_xor(v, 8);
        if (n16 == 0) s_lds[t] = v;
    }

    // ---- Phase 3: y-GEMM, wave wv owns nt = wv*4 .. wv*4+3 ----
    f32x4 acc[4];
#pragma unroll
    for (int i = 0; i < 4; ++i) acc[i] = (f32x4){0.f, 0.f, 0.f, 0.f};
    const f16* bP = w1t + (size_t)(wv * 4) * 16 * 512 + lane * 8;
#pragma unroll
    for (int kt = 0; kt < 16; ++kt) {
        f16x8 a  = *(const f16x8*)&xs[l15][kt * 32 + q * 8];
        f16x8 f0 = *(const f16x8*)(bP + (size_t)(0 * 16 + kt) * 512);
        f16x8 f1 = *(const f16x8*)(bP + (size_t)(1 * 16 + kt) * 512);
        f16x8 f2 = *(const f16x8*)(bP + (size_t)(2 * 16 + kt) * 512);
        f16x8 f3 = *(const f16x8*)(bP + (size_t)(3 * 16 + kt) * 512);
        acc[0] = __builtin_amdgcn_mfma_f32_16x16x32_f16(a, f0, acc[0], 0, 0, 0);
        acc[1] = __builtin_amdgcn_mfma_f32_16x16x32_f16(a, f1, acc[1], 0, 0, 0);
        acc[2] = __builtin_amdgcn_mfma_f32_16x16x32_f16(a, f2, acc[2], 0, 0, 0);
        acc[3] = __builtin_amdgcn_mfma_f32_16x16x32_f16(a, f3, acc[3], 0, 0, 0);
    }
    __syncthreads();   // s_lds visible to all waves

    // ---- Phase 4: epilogue in place (each (t,d) owned by exactly 1 lane) ----
#pragma unroll
    for (int i = 0; i < 4; ++i) {
        int d = (wv * 4 + i) * 16 + l15;
        float bb = b1[d];
#pragma unroll
        for (int r = 0; r < 4; ++r) {
            int t = q * 4 + r;
            xf[t][d] = xf[t][d] * softplusf(acc[i][r] + bb) * s_lds[t];
        }
    }
    __syncthreads();

    // coalesced copy-out: block's y region is contiguous 16x512 f32
#pragma unroll
    for (int it = 0; it < 4; ++it) {
        int f   = tid + 512 * it;
        int row = f >> 7;
        int c4  = (f & 127) * 4;
        *(float4*)(y + (size_t)(tb + row) * DDIM + c4) =
            *(const float4*)&xf[row][c4];
    }
}

// ---------------------------------------------------------------------------
extern "C" void kernel_launch(void* const* d_in, const int* in_sizes, int n_in,
                              void* d_out, int out_size, void* d_ws, size_t ws_size,
                              hipStream_t stream)
{
    (void)n_in; (void)out_size; (void)ws_size;
    const float* x  = (const float*)d_in[0];
    const float* W1 = (const float*)d_in[1];
    const float* b1 = (const float*)d_in[2];
    const float* W2 = (const float*)d_in[3];
    const float* b2 = (const float*)d_in[4];
    const float* W3 = (const float*)d_in[5];
    const float* b3 = (const float*)d_in[6];
    // d_in[7] = A unused (multiplies h=0)
    float* y = (float*)d_out;

    char* ws = (char*)d_ws;
    f16* w1t = (f16*)ws;                    // 512 KB (32 nt x 16 kt slabs)
    f16* w23 = (f16*)(ws + (512 << 10));    // 128 KB (8 nt x 16 kt slabs)

    const int M = in_sizes[0] / DDIM;       // 4096 tokens

    prep_w<<<20, 256, 0, stream>>>(W1, W2, W3, w1t, w23);
    fused_sy<<<M / 16, 512, 0, stream>>>(x, w1t, w23, b1, b2, b3, y);
}